// Round 1
// baseline (715.176 us; speedup 1.0000x reference)
//
#include <hip/hip_runtime.h>

typedef __bf16 bf16;
typedef __bf16 bf16x4 __attribute__((ext_vector_type(4)));
typedef __bf16 bf16x8 __attribute__((ext_vector_type(8)));
typedef float f32x4 __attribute__((ext_vector_type(4)));

#define S_LEN 2048
#define HID   3584
#define NHEADS 16
#define NKVH   8
#define HDIM   256
#define QKV_O  8192   // (16 + 2*8) * 256
#define O_IN   4096   // 16 * 256

typedef const __attribute__((address_space(1))) void* gp_t;
typedef __attribute__((address_space(3))) void* sp_t;

__device__ __forceinline__ void async16(const void* g, void* s) {
  __builtin_amdgcn_global_load_lds((gp_t)g, (sp_t)s, 16, 0, 0);
}

__device__ __forceinline__ f32x4 mfma16(bf16x8 a, bf16x8 b, f32x4 c) {
  return __builtin_amdgcn_mfma_f32_16x16x32_bf16(a, b, c, 0, 0, 0);
}

// ---------------- fp32 -> bf16 cast (4 elems/thread) ----------------
__global__ __launch_bounds__(256) void cast_kernel(const float* __restrict__ in,
                                                   bf16* __restrict__ out, int n4) {
  int i = blockIdx.x * 256 + threadIdx.x;
  if (i >= n4) return;
  f32x4 v = ((const f32x4*)in)[i];
  bf16x4 o = { (bf16)v[0], (bf16)v[1], (bf16)v[2], (bf16)v[3] };
  ((bf16x4*)out)[i] = o;
}

// ---------------- NT bf16 GEMM: C[M,N] fp32 = A[M,K] * B[N,K]^T ----------------
// m97 structure: 128x128 tile, BK=32, global_load_lds width 16, 2x2 waves x 4x4 MFMA tiles
__global__ __launch_bounds__(256) void gemm_nt(const bf16* __restrict__ A, const bf16* __restrict__ B,
                                               float* __restrict__ C, int M, int N, int K) {
  __shared__ bf16 As[128 * 32];
  __shared__ bf16 Bs[128 * 32];
  int tid = threadIdx.x;
  int lane = tid & 63;
  int bm = blockIdx.y, bn = blockIdx.x;
  int w = tid >> 6, wm = w >> 1, wn = w & 1;
  int fr = lane & 15, fq = lane >> 4;
  int sr = tid >> 2;            // staging row 0..63 (pass adds +64)
  int scol = (tid & 3) * 8;     // staging col in elems
  const bf16* Ag = A + (size_t)(bm * 128 + sr) * K + scol;
  const bf16* Bg = B + (size_t)(bn * 128 + sr) * K + scol;
  bf16* Asl = &As[sr * 32 + scol];
  bf16* Bsl = &Bs[sr * 32 + scol];
  const bf16* Af = &As[(wm * 64 + fr) * 32 + fq * 8];
  const bf16* Bf = &Bs[(wn * 64 + fr) * 32 + fq * 8];
  f32x4 acc[4][4];
#pragma unroll
  for (int i = 0; i < 4; i++)
#pragma unroll
    for (int j = 0; j < 4; j++) { f32x4 z = {0.f, 0.f, 0.f, 0.f}; acc[i][j] = z; }
  for (int k0 = 0; k0 < K; k0 += 32) {
    __syncthreads();
    async16(Ag + k0, Asl);
    async16(Ag + (size_t)64 * K + k0, Asl + 64 * 32);
    async16(Bg + k0, Bsl);
    async16(Bg + (size_t)64 * K + k0, Bsl + 64 * 32);
    __syncthreads();
    bf16x8 a[4], b[4];
#pragma unroll
    for (int t = 0; t < 4; t++) a[t] = *(const bf16x8*)(Af + t * 16 * 32);
#pragma unroll
    for (int t = 0; t < 4; t++) b[t] = *(const bf16x8*)(Bf + t * 16 * 32);
#pragma unroll
    for (int i = 0; i < 4; i++)
#pragma unroll
      for (int j = 0; j < 4; j++) acc[i][j] = mfma16(a[i], b[j], acc[i][j]);
  }
  int row0 = bm * 128 + wm * 64 + fq * 4;
  int col0 = bn * 128 + wn * 64 + fr;
#pragma unroll
  for (int i = 0; i < 4; i++)
#pragma unroll
    for (int j = 0; j < 4; j++)
#pragma unroll
      for (int r = 0; r < 4; r++)
        C[(size_t)(row0 + i * 16 + r) * N + col0 + j * 16] = acc[i][j][r];
}

// ---------------- RMSNorm + RoPE + q-scale; one wave per (s, head) ----------------
__global__ __launch_bounds__(256) void qk_norm_rope(const float* __restrict__ qkv,
                                                    const float* __restrict__ cosb,
                                                    const float* __restrict__ sinb,
                                                    const float* __restrict__ qw,
                                                    const float* __restrict__ kw,
                                                    bf16* __restrict__ qout,
                                                    bf16* __restrict__ kout) {
  int s = blockIdx.x;
  int lane = threadIdx.x & 63;
  int w = threadIdx.x >> 6;
  int d0 = lane * 4;
  int dr = d0 & 127;
  f32x4 cv = *(const f32x4*)(cosb + s * 128 + dr);
  f32x4 sv = *(const f32x4*)(sinb + s * 128 + dr);
  bool hi = lane >= 32;
#pragma unroll
  for (int r = 0; r < 6; r++) {
    int head = r * 4 + w;  // 0..23 : 16 q heads then 8 k heads
    const float* x = qkv + (size_t)s * QKV_O + head * HDIM + d0;
    f32x4 v = *(const f32x4*)x;
    float ss = v[0] * v[0] + v[1] * v[1] + v[2] * v[2] + v[3] * v[3];
#pragma unroll
    for (int off = 32; off > 0; off >>= 1) ss += __shfl_xor(ss, off);
    float scale = rsqrtf(ss * (1.0f / HDIM) + 1e-6f);
    bool isq = head < NHEADS;
    const float* wn = isq ? qw : kw;
    f32x4 wv = *(const f32x4*)(wn + d0);
    float y[4], o[4];
#pragma unroll
    for (int i = 0; i < 4; i++) y[i] = v[i] * scale * (1.0f + wv[i]);
#pragma unroll
    for (int i = 0; i < 4; i++) {
      float py = __shfl_xor(y[i], 32);
      o[i] = hi ? (py * sv[i] + y[i] * cv[i]) : (y[i] * cv[i] - py * sv[i]);
    }
    float mult = isq ? 0.0625f : 1.0f;  // SCALING = 256^-0.5 folded into q
    bf16x4 ov = { (bf16)(o[0] * mult), (bf16)(o[1] * mult), (bf16)(o[2] * mult), (bf16)(o[3] * mult) };
    if (isq) *(bf16x4*)(qout + ((size_t)head * S_LEN + s) * HDIM + d0) = ov;
    else     *(bf16x4*)(kout + ((size_t)(head - NHEADS) * S_LEN + s) * HDIM + d0) = ov;
  }
}

// ---------------- V transpose: qkv fp32 [s][6144+h*256+d] -> vt bf16 [h][d][s] ----------------
__global__ __launch_bounds__(256) void v_transpose(const float* __restrict__ qkv, bf16* __restrict__ vt) {
  __shared__ float tile[64][65];
  int dt = blockIdx.x, st = blockIdx.y, h = blockIdx.z;
  int t = threadIdx.x;
  int d0 = dt * 64, s0 = st * 64;
#pragma unroll
  for (int i = 0; i < 16; i++) {
    int idx = i * 256 + t;
    int r = idx >> 6, c = idx & 63;  // r = s-offset, c = d-offset
    tile[r][c] = qkv[(size_t)(s0 + r) * QKV_O + 6144 + h * HDIM + d0 + c];
  }
  __syncthreads();
#pragma unroll
  for (int i = 0; i < 16; i++) {
    int idx = i * 256 + t;
    int dr = idx >> 6, sc = idx & 63;  // dr = d-offset, sc = s-offset
    vt[((size_t)h * HDIM + d0 + dr) * S_LEN + s0 + sc] = (bf16)tile[sc][dr];
  }
}

// ---------------- Flash attention: 64 q-rows/block, Bk=32, online softmax + softcap ----------------
__global__ __launch_bounds__(256) void attn_kernel(const bf16* __restrict__ q,
                                                   const bf16* __restrict__ kx,
                                                   const bf16* __restrict__ vt,
                                                   bf16* __restrict__ aout) {
  __shared__ bf16 kt[32 * 256];     // K-tile [k'][d], row-rotation swizzled by k'*8 elems
  __shared__ bf16 vtile[256 * 32];  // V-tile [d][k']
  __shared__ bf16 pbuf[4][16 * 32]; // per-wave P staging (C-layout -> A-layout)
  int h = blockIdx.x, qt = blockIdx.y;
  int kvh = h >> 1;  // GQA: repeat -> q head h uses kv head h/2
  int tid = threadIdx.x;
  int lane = tid & 63, w = tid >> 6;
  int fr = lane & 15, fq = lane >> 4;
  int qs = qt * 64;
  // Q fragments (A-operand, row = qs + w*16 + fr), resident in regs for whole loop
  bf16x8 qf[8];
  const bf16* qb = q + ((size_t)h * S_LEN + qs + w * 16 + fr) * HDIM + fq * 8;
#pragma unroll
  for (int i = 0; i < 8; i++) qf[i] = *(const bf16x8*)(qb + i * 32);
  f32x4 acc[16];
#pragma unroll
  for (int i = 0; i < 16; i++) { f32x4 z = {0.f, 0.f, 0.f, 0.f}; acc[i] = z; }
  float mrun[4] = {-1e30f, -1e30f, -1e30f, -1e30f};
  float lrun[4] = {0.f, 0.f, 0.f, 0.f};
  // staging lane roles
  int krow = w * 2 + (lane >> 5);
  int kcolr = (lane & 31) * 8;
  const bf16* kg = kx + (size_t)kvh * S_LEN * HDIM;
  int vd = w * 16 + (lane >> 2);
  int vc = (lane & 3) * 8;
  const bf16* vg = vt + (size_t)kvh * HDIM * S_LEN;
  // swizzled fragment read bases: row r of kt holds K[r][(c + r*8) & 255] at col c
  int rot0 = (fq * 8 - fr * 8) & 255;
  int rot1 = (fq * 8 - fr * 8 - 128) & 255;
  const bf16* kt0 = &kt[fr * 256];
  const bf16* kt1 = &kt[(16 + fr) * 256];
  int kmax = qs + 64;
  for (int k0 = 0; k0 < kmax; k0 += 32) {
    __syncthreads();
#pragma unroll
    for (int p = 0; p < 4; p++) {
      int r = p * 8 + krow;
      int gc = (kcolr + r * 8) & 255;
      async16(kg + (size_t)(k0 + r) * HDIM + gc, &kt[r * 256 + kcolr]);
      int d = p * 64 + vd;
      async16(vg + (size_t)d * S_LEN + k0 + vc, &vtile[d * 32 + vc]);
    }
    __syncthreads();
    // QK^T for two 16-col score tiles
    f32x4 s0 = {0.f, 0.f, 0.f, 0.f}, s1 = {0.f, 0.f, 0.f, 0.f};
#pragma unroll
    for (int kk = 0; kk < 8; kk++) {
      bf16x8 b0 = *(const bf16x8*)(kt0 + ((kk * 32 + rot0) & 255));
      bf16x8 b1 = *(const bf16x8*)(kt1 + ((kk * 32 + rot1) & 255));
      s0 = mfma16(qf[kk], b0, s0);
      s1 = mfma16(qf[kk], b1, s1);
    }
    // softcap + causal mask + online softmax (per C-layout row = fq*4+reg)
    float alpha[4];
#pragma unroll
    for (int reg = 0; reg < 4; reg++) {
      int rowg = qs + w * 16 + fq * 4 + reg;
      float x0 = s0[reg], x1 = s1[reg];
      float e0 = __expf(0.04f * x0);            // tanh(x/50) via exp
      float e1 = __expf(0.04f * x1);
      x0 = 50.0f * (e0 - 1.0f) / (e0 + 1.0f);
      x1 = 50.0f * (e1 - 1.0f) / (e1 + 1.0f);
      x0 = (k0 + fr <= rowg) ? x0 : -1e9f;
      x1 = (k0 + 16 + fr <= rowg) ? x1 : -1e9f;
      float mx = fmaxf(x0, x1);
      mx = fmaxf(mx, __shfl_xor(mx, 1));
      mx = fmaxf(mx, __shfl_xor(mx, 2));
      mx = fmaxf(mx, __shfl_xor(mx, 4));
      mx = fmaxf(mx, __shfl_xor(mx, 8));
      float mn = fmaxf(mrun[reg], mx);
      float a = __expf(mrun[reg] - mn);
      mrun[reg] = mn;
      float p0 = __expf(x0 - mn);
      float p1 = __expf(x1 - mn);
      float rs = p0 + p1;
      rs += __shfl_xor(rs, 1);
      rs += __shfl_xor(rs, 2);
      rs += __shfl_xor(rs, 4);
      rs += __shfl_xor(rs, 8);
      lrun[reg] = lrun[reg] * a + rs;
      alpha[reg] = a;
      pbuf[w][(fq * 4 + reg) * 32 + fr] = (bf16)p0;
      pbuf[w][(fq * 4 + reg) * 32 + 16 + fr] = (bf16)p1;
    }
#pragma unroll
    for (int ct = 0; ct < 16; ct++)
#pragma unroll
      for (int reg = 0; reg < 4; reg++) acc[ct][reg] *= alpha[reg];
    // PV: P in A-layout (same-wave LDS round trip), V^T b128 fragments
    bf16x8 pf = *(const bf16x8*)&pbuf[w][fr * 32 + fq * 8];
#pragma unroll
    for (int ct = 0; ct < 16; ct++) {
      bf16x8 vf = *(const bf16x8*)&vtile[(ct * 16 + fr) * 32 + fq * 8];
      acc[ct] = mfma16(pf, vf, acc[ct]);
    }
  }
  float rl[4];
#pragma unroll
  for (int reg = 0; reg < 4; reg++) rl[reg] = 1.0f / lrun[reg];
#pragma unroll
  for (int ct = 0; ct < 16; ct++)
#pragma unroll
    for (int reg = 0; reg < 4; reg++)
      aout[(size_t)(qs + w * 16 + fq * 4 + reg) * O_IN + h * HDIM + ct * 16 + fr] =
          (bf16)(acc[ct][reg] * rl[reg]);
}

extern "C" void kernel_launch(void* const* d_in, const int* in_sizes, int n_in,
                              void* d_out, int out_size, void* d_ws, size_t ws_size,
                              hipStream_t stream) {
  const float* hidden = (const float*)d_in[0];
  const float* cosb   = (const float*)d_in[1];
  const float* sinb   = (const float*)d_in[2];
  // d_in[3] kv_write_indices == arange(S); d_in[4,5] caches (dead); d_in[6] mask == causal
  const float* wqkv   = (const float*)d_in[7];
  const float* wo     = (const float*)d_in[8];
  const float* qnw    = (const float*)d_in[9];
  const float* knw    = (const float*)d_in[10];
  float* out = (float*)d_out;
  char* ws = (char*)d_ws;
  // workspace layout (bytes)
  bf16*  h_bf    = (bf16*)(ws + 0);          // 2048*3584*2   = 14,680,064
  bf16*  wqkv_bf = (bf16*)(ws + 14680064);   // 8192*3584*2   = 58,720,256
  bf16*  wo_bf   = (bf16*)(ws + 73400320);   // 3584*4096*2   = 29,360,128
  float* qkv     = (float*)(ws + 102760448); // 2048*8192*4   = 67,108,864
  bf16*  qb      = (bf16*)(ws + 169869312);  // 16*2048*256*2 = 16,777,216
  bf16*  kb      = (bf16*)(ws + 186646528);  // 8*2048*256*2  =  8,388,608
  bf16*  vtb     = (bf16*)(ws + 195035136);  // 8*256*2048*2  =  8,388,608
  bf16*  attnb   = (bf16*)(ws + 203423744);  // 2048*4096*2   = 16,777,216

  cast_kernel<<<7168, 256, 0, stream>>>(hidden, h_bf, 1835008);
  cast_kernel<<<28672, 256, 0, stream>>>(wqkv, wqkv_bf, 7340032);
  cast_kernel<<<14336, 256, 0, stream>>>(wo, wo_bf, 3670016);
  gemm_nt<<<dim3(64, 16), 256, 0, stream>>>(h_bf, wqkv_bf, qkv, 2048, 8192, 3584);
  qk_norm_rope<<<2048, 256, 0, stream>>>(qkv, cosb, sinb, qnw, knw, qb, kb);
  v_transpose<<<dim3(4, 32, 8), 256, 0, stream>>>(qkv, vtb);
  attn_kernel<<<dim3(16, 32), 256, 0, stream>>>(qb, kb, vtb, attnb);
  gemm_nt<<<dim3(28, 16), 256, 0, stream>>>(attnb, wo_bf, out, 2048, 3584, 4096);
}

// Round 2
// 655.472 us; speedup vs baseline: 1.0911x; 1.0911x over previous
//
#include <hip/hip_runtime.h>

typedef __bf16 bf16;
typedef __bf16 bf16x4 __attribute__((ext_vector_type(4)));
typedef __bf16 bf16x8 __attribute__((ext_vector_type(8)));
typedef float f32x4 __attribute__((ext_vector_type(4)));

#define S_LEN 2048
#define HID   3584
#define NHEADS 16
#define NKVH   8
#define HDIM   256
#define QKV_O  8192   // (16 + 2*8) * 256
#define O_IN   4096   // 16 * 256

typedef const __attribute__((address_space(1))) void* gp_t;
typedef __attribute__((address_space(3))) void* sp_t;

__device__ __forceinline__ void async16(const void* g, void* s) {
  __builtin_amdgcn_global_load_lds((gp_t)g, (sp_t)s, 16, 0, 0);
}

__device__ __forceinline__ f32x4 mfma16(bf16x8 a, bf16x8 b, f32x4 c) {
  return __builtin_amdgcn_mfma_f32_16x16x32_bf16(a, b, c, 0, 0, 0);
}

// ---------------- fp32 -> bf16 cast (4 elems/thread) ----------------
__global__ __launch_bounds__(256) void cast_kernel(const float* __restrict__ in,
                                                   bf16* __restrict__ out, int n4) {
  int i = blockIdx.x * 256 + threadIdx.x;
  if (i >= n4) return;
  f32x4 v = ((const f32x4*)in)[i];
  bf16x4 o = { (bf16)v[0], (bf16)v[1], (bf16)v[2], (bf16)v[3] };
  ((bf16x4*)out)[i] = o;
}

// ---------------- NT bf16 GEMM: C[M,N] fp32 = A[M,K] * B[N,K]^T ----------------
__global__ __launch_bounds__(256) void gemm_nt(const bf16* __restrict__ A, const bf16* __restrict__ B,
                                               float* __restrict__ C, int M, int N, int K) {
  __shared__ bf16 As[128 * 32];
  __shared__ bf16 Bs[128 * 32];
  int tid = threadIdx.x;
  int lane = tid & 63;
  int bm = blockIdx.y, bn = blockIdx.x;
  int w = tid >> 6, wm = w >> 1, wn = w & 1;
  int fr = lane & 15, fq = lane >> 4;
  int sr = tid >> 2;            // staging row 0..63 (pass adds +64)
  int scol = (tid & 3) * 8;     // staging col in elems
  const bf16* Ag = A + (size_t)(bm * 128 + sr) * K + scol;
  const bf16* Bg = B + (size_t)(bn * 128 + sr) * K + scol;
  bf16* Asl = &As[sr * 32 + scol];
  bf16* Bsl = &Bs[sr * 32 + scol];
  const bf16* Af = &As[(wm * 64 + fr) * 32 + fq * 8];
  const bf16* Bf = &Bs[(wn * 64 + fr) * 32 + fq * 8];
  f32x4 acc[4][4];
#pragma unroll
  for (int i = 0; i < 4; i++)
#pragma unroll
    for (int j = 0; j < 4; j++) { f32x4 z = {0.f, 0.f, 0.f, 0.f}; acc[i][j] = z; }
  for (int k0 = 0; k0 < K; k0 += 32) {
    __syncthreads();
    async16(Ag + k0, Asl);
    async16(Ag + (size_t)64 * K + k0, Asl + 64 * 32);
    async16(Bg + k0, Bsl);
    async16(Bg + (size_t)64 * K + k0, Bsl + 64 * 32);
    __syncthreads();
    bf16x8 a[4], b[4];
#pragma unroll
    for (int t = 0; t < 4; t++) a[t] = *(const bf16x8*)(Af + t * 16 * 32);
#pragma unroll
    for (int t = 0; t < 4; t++) b[t] = *(const bf16x8*)(Bf + t * 16 * 32);
#pragma unroll
    for (int i = 0; i < 4; i++)
#pragma unroll
      for (int j = 0; j < 4; j++) acc[i][j] = mfma16(a[i], b[j], acc[i][j]);
  }
  int row0 = bm * 128 + wm * 64 + fq * 4;
  int col0 = bn * 128 + wn * 64 + fr;
#pragma unroll
  for (int i = 0; i < 4; i++)
#pragma unroll
    for (int j = 0; j < 4; j++)
#pragma unroll
      for (int r = 0; r < 4; r++)
        C[(size_t)(row0 + i * 16 + r) * N + col0 + j * 16] = acc[i][j][r];
}

// ---------------- RMSNorm + RoPE + q-scale; one wave per (s, head) ----------------
__global__ __launch_bounds__(256) void qk_norm_rope(const float* __restrict__ qkv,
                                                    const float* __restrict__ cosb,
                                                    const float* __restrict__ sinb,
                                                    const float* __restrict__ qw,
                                                    const float* __restrict__ kw,
                                                    bf16* __restrict__ qout,
                                                    bf16* __restrict__ kout) {
  int s = blockIdx.x;
  int lane = threadIdx.x & 63;
  int w = threadIdx.x >> 6;
  int d0 = lane * 4;
  int dr = d0 & 127;
  f32x4 cv = *(const f32x4*)(cosb + s * 128 + dr);
  f32x4 sv = *(const f32x4*)(sinb + s * 128 + dr);
  bool hi = lane >= 32;
#pragma unroll
  for (int r = 0; r < 6; r++) {
    int head = r * 4 + w;  // 0..23 : 16 q heads then 8 k heads
    const float* x = qkv + (size_t)s * QKV_O + head * HDIM + d0;
    f32x4 v = *(const f32x4*)x;
    float ss = v[0] * v[0] + v[1] * v[1] + v[2] * v[2] + v[3] * v[3];
#pragma unroll
    for (int off = 32; off > 0; off >>= 1) ss += __shfl_xor(ss, off);
    float scale = rsqrtf(ss * (1.0f / HDIM) + 1e-6f);
    bool isq = head < NHEADS;
    const float* wn = isq ? qw : kw;
    f32x4 wv = *(const f32x4*)(wn + d0);
    float y[4], o[4];
#pragma unroll
    for (int i = 0; i < 4; i++) y[i] = v[i] * scale * (1.0f + wv[i]);
#pragma unroll
    for (int i = 0; i < 4; i++) {
      float py = __shfl_xor(y[i], 32);
      o[i] = hi ? (py * sv[i] + y[i] * cv[i]) : (y[i] * cv[i] - py * sv[i]);
    }
    float mult = isq ? 0.0625f : 1.0f;  // SCALING = 256^-0.5 folded into q
    bf16x4 ov = { (bf16)(o[0] * mult), (bf16)(o[1] * mult), (bf16)(o[2] * mult), (bf16)(o[3] * mult) };
    if (isq) *(bf16x4*)(qout + ((size_t)head * S_LEN + s) * HDIM + d0) = ov;
    else     *(bf16x4*)(kout + ((size_t)(head - NHEADS) * S_LEN + s) * HDIM + d0) = ov;
  }
}

// ---------------- V transpose: qkv fp32 [s][6144+h*256+d] -> vt bf16 [h][d][s] ----------------
__global__ __launch_bounds__(256) void v_transpose(const float* __restrict__ qkv, bf16* __restrict__ vt) {
  __shared__ float tile[64][65];
  int dt = blockIdx.x, st = blockIdx.y, h = blockIdx.z;
  int t = threadIdx.x;
  int d0 = dt * 64, s0 = st * 64;
#pragma unroll
  for (int i = 0; i < 16; i++) {
    int idx = i * 256 + t;
    int r = idx >> 6, c = idx & 63;  // r = s-offset, c = d-offset
    tile[r][c] = qkv[(size_t)(s0 + r) * QKV_O + 6144 + h * HDIM + d0 + c];
  }
  __syncthreads();
#pragma unroll
  for (int i = 0; i < 16; i++) {
    int idx = i * 256 + t;
    int dr = idx >> 6, sc = idx & 63;  // dr = d-offset, sc = s-offset
    vt[((size_t)h * HDIM + d0 + dr) * S_LEN + s0 + sc] = (bf16)tile[sc][dr];
  }
}

// ---------------- Flash attention: 64 q-rows/block, Bk=32 ----------------
// Fixed-max softmax: softcap bounds s to [-50,50]; with M=30,
// p = exp(s-30) in [e^-80, e^20] -- normal range in fp32 AND bf16, so no
// online max / rescale / in-loop reductions needed. Partial l accumulates
// per-lane; acc and l are linear so one final reduce + divide suffices.
// qt remap (y<16 ? y : 47-y) pairs long+short causal blocks on each CU.
#define PSTRIDE 40  // pbuf row stride in bf16 (80 B): breaks 8-way bank conflict, keeps 16B align
__global__ __launch_bounds__(256) void attn_kernel(const bf16* __restrict__ q,
                                                   const bf16* __restrict__ kx,
                                                   const bf16* __restrict__ vt,
                                                   bf16* __restrict__ aout) {
  __shared__ bf16 kt[32 * 256];          // K-tile [k'][d], row-rotation swizzled by k'*8 elems
  __shared__ bf16 vtile[256 * 32];       // V-tile [d][k']
  __shared__ bf16 pbuf[4][16 * PSTRIDE]; // per-wave P staging (C-layout -> A-layout)
  int h = blockIdx.x;
  int y = blockIdx.y;
  int qt = (y < 16) ? y : 47 - y;  // dispatch-balance pairing: CU gets qt + (31-qt)
  int kvh = h >> 1;                // GQA: q head h uses kv head h/2
  int tid = threadIdx.x;
  int lane = tid & 63, w = tid >> 6;
  int fr = lane & 15, fq = lane >> 4;
  int qs = qt * 64;
  bf16x8 qf[8];
  const bf16* qb = q + ((size_t)h * S_LEN + qs + w * 16 + fr) * HDIM + fq * 8;
#pragma unroll
  for (int i = 0; i < 8; i++) qf[i] = *(const bf16x8*)(qb + i * 32);
  f32x4 acc[16];
#pragma unroll
  for (int i = 0; i < 16; i++) { f32x4 z = {0.f, 0.f, 0.f, 0.f}; acc[i] = z; }
  float lsum[4] = {0.f, 0.f, 0.f, 0.f};
  // staging lane roles
  int krow = w * 2 + (lane >> 5);
  int kcolr = (lane & 31) * 8;
  const bf16* kg = kx + (size_t)kvh * S_LEN * HDIM;
  int vd = w * 16 + (lane >> 2);
  int vc = (lane & 3) * 8;
  const bf16* vg = vt + (size_t)kvh * HDIM * S_LEN;
  // swizzled fragment read bases: row r of kt holds K[r][(c + r*8) & 255] at col c
  int rot0 = (fq * 8 - fr * 8) & 255;
  int rot1 = (fq * 8 - fr * 8 - 128) & 255;
  const bf16* kt0 = &kt[fr * 256];
  const bf16* kt1 = &kt[(16 + fr) * 256];
  int kmax = qs + 64;
  for (int k0 = 0; k0 < kmax; k0 += 32) {
    __syncthreads();
#pragma unroll
    for (int p = 0; p < 4; p++) {
      int r = p * 8 + krow;
      int gc = (kcolr + r * 8) & 255;
      async16(kg + (size_t)(k0 + r) * HDIM + gc, &kt[r * 256 + kcolr]);
      int d = p * 64 + vd;
      async16(vg + (size_t)d * S_LEN + k0 + vc, &vtile[d * 32 + vc]);
    }
    __syncthreads();
    // QK^T for two 16-col score tiles
    f32x4 s0 = {0.f, 0.f, 0.f, 0.f}, s1 = {0.f, 0.f, 0.f, 0.f};
#pragma unroll
    for (int kk = 0; kk < 8; kk++) {
      bf16x8 b0 = *(const bf16x8*)(kt0 + ((kk * 32 + rot0) & 255));
      bf16x8 b1 = *(const bf16x8*)(kt1 + ((kk * 32 + rot1) & 255));
      s0 = mfma16(qf[kk], b0, s0);
      s1 = mfma16(qf[kk], b1, s1);
    }
    // softcap + causal mask + fixed-max exp (p = exp(softcap(x) - 30))
    // softcap(x)-30 = 20 - 100/(u+1), u = e^(x/25) = exp2(x * 0.04*log2e)
    // p = exp2(28.853901 - 144.26950/(u+1))
#pragma unroll
    for (int reg = 0; reg < 4; reg++) {
      int rowg = qs + w * 16 + fq * 4 + reg;
      float u0 = __builtin_amdgcn_exp2f(0.057707802f * s0[reg]);
      float u1 = __builtin_amdgcn_exp2f(0.057707802f * s1[reg]);
      float p0 = __builtin_amdgcn_exp2f(28.853901f - 144.26950f * __builtin_amdgcn_rcpf(u0 + 1.0f));
      float p1 = __builtin_amdgcn_exp2f(28.853901f - 144.26950f * __builtin_amdgcn_rcpf(u1 + 1.0f));
      p0 = (k0 + fr <= rowg) ? p0 : 0.0f;
      p1 = (k0 + 16 + fr <= rowg) ? p1 : 0.0f;
      lsum[reg] += p0 + p1;
      pbuf[w][(fq * 4 + reg) * PSTRIDE + fr] = (bf16)p0;
      pbuf[w][(fq * 4 + reg) * PSTRIDE + 16 + fr] = (bf16)p1;
    }
    // PV: P in A-layout (same-wave LDS round trip), V^T b128 fragments
    bf16x8 pf = *(const bf16x8*)&pbuf[w][fr * PSTRIDE + fq * 8];
#pragma unroll
    for (int ct = 0; ct < 16; ct++) {
      bf16x8 vf = *(const bf16x8*)&vtile[(ct * 16 + fr) * 32 + fq * 8];
      acc[ct] = mfma16(pf, vf, acc[ct]);
    }
  }
  // final l reduction over the 16 fr lanes of each row, then divide
  float rl[4];
#pragma unroll
  for (int reg = 0; reg < 4; reg++) {
    float l = lsum[reg];
    l += __shfl_xor(l, 1);
    l += __shfl_xor(l, 2);
    l += __shfl_xor(l, 4);
    l += __shfl_xor(l, 8);
    rl[reg] = 1.0f / l;
  }
#pragma unroll
  for (int ct = 0; ct < 16; ct++)
#pragma unroll
    for (int reg = 0; reg < 4; reg++)
      aout[(size_t)(qs + w * 16 + fq * 4 + reg) * O_IN + h * HDIM + ct * 16 + fr] =
          (bf16)(acc[ct][reg] * rl[reg]);
}

extern "C" void kernel_launch(void* const* d_in, const int* in_sizes, int n_in,
                              void* d_out, int out_size, void* d_ws, size_t ws_size,
                              hipStream_t stream) {
  const float* hidden = (const float*)d_in[0];
  const float* cosb   = (const float*)d_in[1];
  const float* sinb   = (const float*)d_in[2];
  const float* wqkv   = (const float*)d_in[7];
  const float* wo     = (const float*)d_in[8];
  const float* qnw    = (const float*)d_in[9];
  const float* knw    = (const float*)d_in[10];
  float* out = (float*)d_out;
  char* ws = (char*)d_ws;
  bf16*  h_bf    = (bf16*)(ws + 0);          // 2048*3584*2   = 14,680,064
  bf16*  wqkv_bf = (bf16*)(ws + 14680064);   // 8192*3584*2   = 58,720,256
  bf16*  wo_bf   = (bf16*)(ws + 73400320);   // 3584*4096*2   = 29,360,128
  float* qkv     = (float*)(ws + 102760448); // 2048*8192*4   = 67,108,864
  bf16*  qb      = (bf16*)(ws + 169869312);  // 16*2048*256*2 = 16,777,216
  bf16*  kb      = (bf16*)(ws + 186646528);  // 8*2048*256*2  =  8,388,608
  bf16*  vtb     = (bf16*)(ws + 195035136);  // 8*256*2048*2  =  8,388,608
  bf16*  attnb   = (bf16*)(ws + 203423744);  // 2048*4096*2   = 16,777,216

  cast_kernel<<<7168, 256, 0, stream>>>(hidden, h_bf, 1835008);
  cast_kernel<<<28672, 256, 0, stream>>>(wqkv, wqkv_bf, 7340032);
  cast_kernel<<<14336, 256, 0, stream>>>(wo, wo_bf, 3670016);
  gemm_nt<<<dim3(64, 16), 256, 0, stream>>>(h_bf, wqkv_bf, qkv, 2048, 8192, 3584);
  qk_norm_rope<<<2048, 256, 0, stream>>>(qkv, cosb, sinb, qnw, knw, qb, kb);
  v_transpose<<<dim3(4, 32, 8), 256, 0, stream>>>(qkv, vtb);
  attn_kernel<<<dim3(16, 32), 256, 0, stream>>>(qb, kb, vtb, attnb);
  gemm_nt<<<dim3(28, 16), 256, 0, stream>>>(attnb, wo_bf, out, 2048, 3584, 4096);
}

// Round 3
// 651.289 us; speedup vs baseline: 1.0981x; 1.0064x over previous
//
#include <hip/hip_runtime.h>

typedef __bf16 bf16;
typedef __bf16 bf16x4 __attribute__((ext_vector_type(4)));
typedef __bf16 bf16x8 __attribute__((ext_vector_type(8)));
typedef float f32x4 __attribute__((ext_vector_type(4)));

#define S_LEN 2048
#define HID   3584
#define NHEADS 16
#define NKVH   8
#define HDIM   256
#define QKV_O  8192   // (16 + 2*8) * 256
#define O_IN   4096   // 16 * 256

typedef const __attribute__((address_space(1))) void* gp_t;
typedef __attribute__((address_space(3))) void* sp_t;

__device__ __forceinline__ void async16(const void* g, void* s) {
  __builtin_amdgcn_global_load_lds((gp_t)g, (sp_t)s, 16, 0, 0);
}

__device__ __forceinline__ f32x4 mfma16(bf16x8 a, bf16x8 b, f32x4 c) {
  return __builtin_amdgcn_mfma_f32_16x16x32_bf16(a, b, c, 0, 0, 0);
}

// ---------------- fp32 -> bf16 cast (4 elems/thread) ----------------
__global__ __launch_bounds__(256) void cast_kernel(const float* __restrict__ in,
                                                   bf16* __restrict__ out, int n4) {
  int i = blockIdx.x * 256 + threadIdx.x;
  if (i >= n4) return;
  f32x4 v = ((const f32x4*)in)[i];
  bf16x4 o = { (bf16)v[0], (bf16)v[1], (bf16)v[2], (bf16)v[3] };
  ((bf16x4*)out)[i] = o;
}

// ---------------- NT bf16 GEMM: C[M,N] fp32 = A[M,K] * B[N,K]^T ----------------
// m97 structure + XOR chunk swizzle: LDS slot c of row r holds k-chunk c^((r>>1)&3).
// Staging permutes the GLOBAL address per lane (LDS dest must stay base+lane*16 for
// global_load_lds); fragment reads un-permute. Kills the 8-way ds_read_b128 bank
// conflict of the plain stride-64B layout (even-fr lanes now 2-way = free, m136).
__global__ __launch_bounds__(256) void gemm_nt(const bf16* __restrict__ A, const bf16* __restrict__ B,
                                               float* __restrict__ C, int M, int N, int K) {
  __shared__ bf16 As[128 * 32];
  __shared__ bf16 Bs[128 * 32];
  int tid = threadIdx.x;
  int lane = tid & 63;
  int bm = blockIdx.y, bn = blockIdx.x;
  int w = tid >> 6, wm = w >> 1, wn = w & 1;
  int fr = lane & 15, fq = lane >> 4;
  int sr = tid >> 2;                        // staging row 0..63 (pass adds +64; (r+64)>>1 & 3 == (r>>1)&3)
  int sw = (sr >> 1) & 3;                   // row swizzle
  int scol = (((tid & 3) ^ sw) * 8);        // permuted GLOBAL k-chunk
  const bf16* Ag = A + (size_t)(bm * 128 + sr) * K + scol;
  const bf16* Bg = B + (size_t)(bn * 128 + sr) * K + scol;
  bf16* Asl = &As[sr * 32 + (tid & 3) * 8]; // lane-linear LDS dest (= base + lane*16B)
  bf16* Bsl = &Bs[sr * 32 + (tid & 3) * 8];
  int fsw = (fr >> 1) & 3;
  const bf16* Af = &As[(wm * 64 + fr) * 32 + (fq ^ fsw) * 8];
  const bf16* Bf = &Bs[(wn * 64 + fr) * 32 + (fq ^ fsw) * 8];
  f32x4 acc[4][4];
#pragma unroll
  for (int i = 0; i < 4; i++)
#pragma unroll
    for (int j = 0; j < 4; j++) { f32x4 z = {0.f, 0.f, 0.f, 0.f}; acc[i][j] = z; }
  for (int k0 = 0; k0 < K; k0 += 32) {
    __syncthreads();
    async16(Ag + k0, Asl);
    async16(Ag + (size_t)64 * K + k0, Asl + 64 * 32);
    async16(Bg + k0, Bsl);
    async16(Bg + (size_t)64 * K + k0, Bsl + 64 * 32);
    __syncthreads();
    bf16x8 a[4], b[4];
#pragma unroll
    for (int t = 0; t < 4; t++) a[t] = *(const bf16x8*)(Af + t * 16 * 32);
#pragma unroll
    for (int t = 0; t < 4; t++) b[t] = *(const bf16x8*)(Bf + t * 16 * 32);
#pragma unroll
    for (int i = 0; i < 4; i++)
#pragma unroll
      for (int j = 0; j < 4; j++) acc[i][j] = mfma16(a[i], b[j], acc[i][j]);
  }
  int row0 = bm * 128 + wm * 64 + fq * 4;
  int col0 = bn * 128 + wn * 64 + fr;
#pragma unroll
  for (int i = 0; i < 4; i++)
#pragma unroll
    for (int j = 0; j < 4; j++)
#pragma unroll
      for (int r = 0; r < 4; r++)
        C[(size_t)(row0 + i * 16 + r) * N + col0 + j * 16] = acc[i][j][r];
}

// ---------------- RMSNorm + RoPE + q-scale; one wave per (s, head) ----------------
__global__ __launch_bounds__(256) void qk_norm_rope(const float* __restrict__ qkv,
                                                    const float* __restrict__ cosb,
                                                    const float* __restrict__ sinb,
                                                    const float* __restrict__ qw,
                                                    const float* __restrict__ kw,
                                                    bf16* __restrict__ qout,
                                                    bf16* __restrict__ kout) {
  int s = blockIdx.x;
  int lane = threadIdx.x & 63;
  int w = threadIdx.x >> 6;
  int d0 = lane * 4;
  int dr = d0 & 127;
  f32x4 cv = *(const f32x4*)(cosb + s * 128 + dr);
  f32x4 sv = *(const f32x4*)(sinb + s * 128 + dr);
  bool hi = lane >= 32;
#pragma unroll
  for (int r = 0; r < 6; r++) {
    int head = r * 4 + w;  // 0..23 : 16 q heads then 8 k heads
    const float* x = qkv + (size_t)s * QKV_O + head * HDIM + d0;
    f32x4 v = *(const f32x4*)x;
    float ss = v[0] * v[0] + v[1] * v[1] + v[2] * v[2] + v[3] * v[3];
#pragma unroll
    for (int off = 32; off > 0; off >>= 1) ss += __shfl_xor(ss, off);
    float scale = rsqrtf(ss * (1.0f / HDIM) + 1e-6f);
    bool isq = head < NHEADS;
    const float* wn = isq ? qw : kw;
    f32x4 wv = *(const f32x4*)(wn + d0);
    float y[4], o[4];
#pragma unroll
    for (int i = 0; i < 4; i++) y[i] = v[i] * scale * (1.0f + wv[i]);
#pragma unroll
    for (int i = 0; i < 4; i++) {
      float py = __shfl_xor(y[i], 32);
      o[i] = hi ? (py * sv[i] + y[i] * cv[i]) : (y[i] * cv[i] - py * sv[i]);
    }
    float mult = isq ? 0.0625f : 1.0f;  // SCALING = 256^-0.5 folded into q
    bf16x4 ov = { (bf16)(o[0] * mult), (bf16)(o[1] * mult), (bf16)(o[2] * mult), (bf16)(o[3] * mult) };
    if (isq) *(bf16x4*)(qout + ((size_t)head * S_LEN + s) * HDIM + d0) = ov;
    else     *(bf16x4*)(kout + ((size_t)(head - NHEADS) * S_LEN + s) * HDIM + d0) = ov;
  }
}

// ---------------- V transpose: qkv fp32 [s][6144+h*256+d] -> vt bf16 [h][d][s] ----------------
__global__ __launch_bounds__(256) void v_transpose(const float* __restrict__ qkv, bf16* __restrict__ vt) {
  __shared__ float tile[64][65];
  int dt = blockIdx.x, st = blockIdx.y, h = blockIdx.z;
  int t = threadIdx.x;
  int d0 = dt * 64, s0 = st * 64;
#pragma unroll
  for (int i = 0; i < 16; i++) {
    int idx = i * 256 + t;
    int r = idx >> 6, c = idx & 63;  // r = s-offset, c = d-offset
    tile[r][c] = qkv[(size_t)(s0 + r) * QKV_O + 6144 + h * HDIM + d0 + c];
  }
  __syncthreads();
#pragma unroll
  for (int i = 0; i < 16; i++) {
    int idx = i * 256 + t;
    int dr = idx >> 6, sc = idx & 63;  // dr = d-offset, sc = s-offset
    vt[((size_t)h * HDIM + d0 + dr) * S_LEN + s0 + sc] = (bf16)tile[sc][dr];
  }
}

// ---------------- Flash attention: 64 q-rows/block, Bk=32 ----------------
// Fixed-max softmax (softcap bounds s to [-50,50]; p=exp(s-30) always normal).
// V-tile now XOR-chunk-swizzled like gemm_nt to kill its 8-way read conflict.
#define PSTRIDE 40  // pbuf row stride in bf16 (80 B): conflict-free, keeps 16B align
__global__ __launch_bounds__(256) void attn_kernel(const bf16* __restrict__ q,
                                                   const bf16* __restrict__ kx,
                                                   const bf16* __restrict__ vt,
                                                   bf16* __restrict__ aout) {
  __shared__ bf16 kt[32 * 256];          // K-tile [k'][d], row-rotation swizzled by k'*8 elems
  __shared__ bf16 vtile[256 * 32];       // V-tile [d][k'], XOR chunk swizzle on k'
  __shared__ bf16 pbuf[4][16 * PSTRIDE]; // per-wave P staging (C-layout -> A-layout)
  int h = blockIdx.x;
  int y = blockIdx.y;
  int qt = (y < 16) ? y : 47 - y;  // dispatch-balance pairing: CU gets qt + (31-qt)
  int kvh = h >> 1;                // GQA: q head h uses kv head h/2
  int tid = threadIdx.x;
  int lane = tid & 63, w = tid >> 6;
  int fr = lane & 15, fq = lane >> 4;
  int qs = qt * 64;
  bf16x8 qf[8];
  const bf16* qb = q + ((size_t)h * S_LEN + qs + w * 16 + fr) * HDIM + fq * 8;
#pragma unroll
  for (int i = 0; i < 8; i++) qf[i] = *(const bf16x8*)(qb + i * 32);
  f32x4 acc[16];
#pragma unroll
  for (int i = 0; i < 16; i++) { f32x4 z = {0.f, 0.f, 0.f, 0.f}; acc[i] = z; }
  float lsum[4] = {0.f, 0.f, 0.f, 0.f};
  // staging lane roles
  int krow = w * 2 + (lane >> 5);
  int kcolr = (lane & 31) * 8;
  const bf16* kg = kx + (size_t)kvh * S_LEN * HDIM;
  int vd = w * 16 + (lane >> 2);
  int vsw = (vd >> 1) & 3;                      // V XOR swizzle
  int vcl = (lane & 3) * 8;                     // LDS chunk slot (lane-linear)
  int vcg = (((lane & 3) ^ vsw) * 8);           // permuted global chunk
  const bf16* vg = vt + (size_t)kvh * HDIM * S_LEN;
  // swizzled fragment read bases: row r of kt holds K[r][(c + r*8) & 255] at col c
  int rot0 = (fq * 8 - fr * 8) & 255;
  int rot1 = (fq * 8 - fr * 8 - 128) & 255;
  const bf16* kt0 = &kt[fr * 256];
  const bf16* kt1 = &kt[(16 + fr) * 256];
  int fsw = (fr >> 1) & 3;
  int kmax = qs + 64;
  for (int k0 = 0; k0 < kmax; k0 += 32) {
    __syncthreads();
#pragma unroll
    for (int p = 0; p < 4; p++) {
      int r = p * 8 + krow;
      int gc = (kcolr + r * 8) & 255;
      async16(kg + (size_t)(k0 + r) * HDIM + gc, &kt[r * 256 + kcolr]);
      int d = p * 64 + vd;
      async16(vg + (size_t)d * S_LEN + k0 + vcg, &vtile[d * 32 + vcl]);
    }
    __syncthreads();
    // QK^T for two 16-col score tiles
    f32x4 s0 = {0.f, 0.f, 0.f, 0.f}, s1 = {0.f, 0.f, 0.f, 0.f};
#pragma unroll
    for (int kk = 0; kk < 8; kk++) {
      bf16x8 b0 = *(const bf16x8*)(kt0 + ((kk * 32 + rot0) & 255));
      bf16x8 b1 = *(const bf16x8*)(kt1 + ((kk * 32 + rot1) & 255));
      s0 = mfma16(qf[kk], b0, s0);
      s1 = mfma16(qf[kk], b1, s1);
    }
    // softcap + causal mask + fixed-max exp: p = exp2(28.853901 - 144.26950/(u+1)),
    // u = exp2(x * 0.04*log2e)
#pragma unroll
    for (int reg = 0; reg < 4; reg++) {
      int rowg = qs + w * 16 + fq * 4 + reg;
      float u0 = __builtin_amdgcn_exp2f(0.057707802f * s0[reg]);
      float u1 = __builtin_amdgcn_exp2f(0.057707802f * s1[reg]);
      float p0 = __builtin_amdgcn_exp2f(28.853901f - 144.26950f * __builtin_amdgcn_rcpf(u0 + 1.0f));
      float p1 = __builtin_amdgcn_exp2f(28.853901f - 144.26950f * __builtin_amdgcn_rcpf(u1 + 1.0f));
      p0 = (k0 + fr <= rowg) ? p0 : 0.0f;
      p1 = (k0 + 16 + fr <= rowg) ? p1 : 0.0f;
      lsum[reg] += p0 + p1;
      pbuf[w][(fq * 4 + reg) * PSTRIDE + fr] = (bf16)p0;
      pbuf[w][(fq * 4 + reg) * PSTRIDE + 16 + fr] = (bf16)p1;
    }
    // PV: P in A-layout (same-wave LDS round trip), V^T b128 fragments (swizzled)
    bf16x8 pf = *(const bf16x8*)&pbuf[w][fr * PSTRIDE + fq * 8];
#pragma unroll
    for (int ct = 0; ct < 16; ct++) {
      bf16x8 vf = *(const bf16x8*)&vtile[(ct * 16 + fr) * 32 + (fq ^ fsw) * 8];
      acc[ct] = mfma16(pf, vf, acc[ct]);
    }
  }
  // final l reduction over the 16 fr lanes of each row, then divide
  float rl[4];
#pragma unroll
  for (int reg = 0; reg < 4; reg++) {
    float l = lsum[reg];
    l += __shfl_xor(l, 1);
    l += __shfl_xor(l, 2);
    l += __shfl_xor(l, 4);
    l += __shfl_xor(l, 8);
    rl[reg] = 1.0f / l;
  }
#pragma unroll
  for (int ct = 0; ct < 16; ct++)
#pragma unroll
    for (int reg = 0; reg < 4; reg++)
      aout[(size_t)(qs + w * 16 + fq * 4 + reg) * O_IN + h * HDIM + ct * 16 + fr] =
          (bf16)(acc[ct][reg] * rl[reg]);
}

extern "C" void kernel_launch(void* const* d_in, const int* in_sizes, int n_in,
                              void* d_out, int out_size, void* d_ws, size_t ws_size,
                              hipStream_t stream) {
  const float* hidden = (const float*)d_in[0];
  const float* cosb   = (const float*)d_in[1];
  const float* sinb   = (const float*)d_in[2];
  const float* wqkv   = (const float*)d_in[7];
  const float* wo     = (const float*)d_in[8];
  const float* qnw    = (const float*)d_in[9];
  const float* knw    = (const float*)d_in[10];
  float* out = (float*)d_out;
  char* ws = (char*)d_ws;
  bf16*  h_bf    = (bf16*)(ws + 0);          // 2048*3584*2   = 14,680,064
  bf16*  wqkv_bf = (bf16*)(ws + 14680064);   // 8192*3584*2   = 58,720,256
  bf16*  wo_bf   = (bf16*)(ws + 73400320);   // 3584*4096*2   = 29,360,128
  float* qkv     = (float*)(ws + 102760448); // 2048*8192*4   = 67,108,864
  bf16*  qb      = (bf16*)(ws + 169869312);  // 16*2048*256*2 = 16,777,216
  bf16*  kb      = (bf16*)(ws + 186646528);  // 8*2048*256*2  =  8,388,608
  bf16*  vtb     = (bf16*)(ws + 195035136);  // 8*256*2048*2  =  8,388,608
  bf16*  attnb   = (bf16*)(ws + 203423744);  // 2048*4096*2   = 16,777,216

  cast_kernel<<<7168, 256, 0, stream>>>(hidden, h_bf, 1835008);
  cast_kernel<<<28672, 256, 0, stream>>>(wqkv, wqkv_bf, 7340032);
  cast_kernel<<<14336, 256, 0, stream>>>(wo, wo_bf, 3670016);
  gemm_nt<<<dim3(64, 16), 256, 0, stream>>>(h_bf, wqkv_bf, qkv, 2048, 8192, 3584);
  qk_norm_rope<<<2048, 256, 0, stream>>>(qkv, cosb, sinb, qnw, knw, qb, kb);
  v_transpose<<<dim3(4, 32, 8), 256, 0, stream>>>(qkv, vtb);
  attn_kernel<<<dim3(16, 32), 256, 0, stream>>>(qb, kb, vtb, attnb);
  gemm_nt<<<dim3(28, 16), 256, 0, stream>>>(attnb, wo_bf, out, 2048, 3584, 4096);
}

// Round 4
// 643.327 us; speedup vs baseline: 1.1117x; 1.0124x over previous
//
#include <hip/hip_runtime.h>

typedef __bf16 bf16;
typedef __bf16 bf16x4 __attribute__((ext_vector_type(4)));
typedef __bf16 bf16x8 __attribute__((ext_vector_type(8)));
typedef float f32x4 __attribute__((ext_vector_type(4)));

#define S_LEN 2048
#define HID   3584
#define NHEADS 16
#define NKVH   8
#define HDIM   256
#define QKV_O  8192   // (16 + 2*8) * 256
#define O_IN   4096   // 16 * 256

typedef const __attribute__((address_space(1))) void* gp_t;
typedef __attribute__((address_space(3))) void* sp_t;

__device__ __forceinline__ void async16(const void* g, void* s) {
  __builtin_amdgcn_global_load_lds((gp_t)g, (sp_t)s, 16, 0, 0);
}

__device__ __forceinline__ f32x4 mfma16(bf16x8 a, bf16x8 b, f32x4 c) {
  return __builtin_amdgcn_mfma_f32_16x16x32_bf16(a, b, c, 0, 0, 0);
}

// ---------------- fp32 -> bf16 cast (4 elems/thread) ----------------
__global__ __launch_bounds__(256) void cast_kernel(const float* __restrict__ in,
                                                   bf16* __restrict__ out, int n4) {
  int i = blockIdx.x * 256 + threadIdx.x;
  if (i >= n4) return;
  f32x4 v = ((const f32x4*)in)[i];
  bf16x4 o = { (bf16)v[0], (bf16)v[1], (bf16)v[2], (bf16)v[3] };
  ((bf16x4*)out)[i] = o;
}

// ---------------- NT bf16 GEMM: C[M,N] fp32 = A[M,K] * B[N,K]^T ----------------
// BK=64 variant: 32 MFMA per barrier pair (AITER-like amortization of the
// vmcnt(0)+s_barrier drain), 8 async16 in flight per drain. XOR chunk swizzle
// for row stride 128B: slot c of row r holds k-chunk c^(r&7); fragment read
// slot (ks*4+fq)^(fr&7) -> 2 lanes per 4-bank group = conflict-free (m136).
// LDS 32 KB/block -> still 4 blocks/CU (avoids m132's occupancy cliff).
__global__ __launch_bounds__(256) void gemm_nt(const bf16* __restrict__ A, const bf16* __restrict__ B,
                                               float* __restrict__ C, int M, int N, int K) {
  __shared__ bf16 As[128 * 64];
  __shared__ bf16 Bs[128 * 64];
  int tid = threadIdx.x;
  int lane = tid & 63;
  int bm = blockIdx.y, bn = blockIdx.x;
  int w = tid >> 6, wm = w >> 1, wn = w & 1;
  int fr = lane & 15, fq = lane >> 4;
  int sr = tid >> 3;                // staging row 0..31 (passes add +32; 32 = 0 mod 8)
  int sc = tid & 7;                 // LDS slot chunk (lane-linear dest)
  int cg = sc ^ (sr & 7);           // permuted GLOBAL chunk, pass-invariant
  const bf16* Ag = A + (size_t)(bm * 128 + sr) * K + cg * 8;
  const bf16* Bg = B + (size_t)(bn * 128 + sr) * K + cg * 8;
  bf16* Asl = &As[sr * 64 + sc * 8];
  bf16* Bsl = &Bs[sr * 64 + sc * 8];
  const bf16* Af = &As[(wm * 64 + fr) * 64];
  const bf16* Bf = &Bs[(wn * 64 + fr) * 64];
  int fsw = fr & 7;
  int fo0 = ((fq ^ fsw) * 8);        // ks=0 chunk cc=fq, un-swizzled slot
  int fo1 = (((4 + fq) ^ fsw) * 8);  // ks=1 chunk cc=4+fq
  f32x4 acc[4][4];
#pragma unroll
  for (int i = 0; i < 4; i++)
#pragma unroll
    for (int j = 0; j < 4; j++) { f32x4 z = {0.f, 0.f, 0.f, 0.f}; acc[i][j] = z; }
  for (int k0 = 0; k0 < K; k0 += 64) {
    __syncthreads();
#pragma unroll
    for (int p = 0; p < 4; p++) {
      async16(Ag + k0 + (size_t)(p * 32) * K, Asl + p * 32 * 64);
      async16(Bg + k0 + (size_t)(p * 32) * K, Bsl + p * 32 * 64);
    }
    __syncthreads();
#pragma unroll
    for (int ks = 0; ks < 2; ks++) {
      int fo = ks ? fo1 : fo0;
      bf16x8 a[4], b[4];
#pragma unroll
      for (int t = 0; t < 4; t++) a[t] = *(const bf16x8*)(Af + t * 16 * 64 + fo);
#pragma unroll
      for (int t = 0; t < 4; t++) b[t] = *(const bf16x8*)(Bf + t * 16 * 64 + fo);
#pragma unroll
      for (int i = 0; i < 4; i++)
#pragma unroll
        for (int j = 0; j < 4; j++) acc[i][j] = mfma16(a[i], b[j], acc[i][j]);
    }
  }
  int row0 = bm * 128 + wm * 64 + fq * 4;
  int col0 = bn * 128 + wn * 64 + fr;
#pragma unroll
  for (int i = 0; i < 4; i++)
#pragma unroll
    for (int j = 0; j < 4; j++)
#pragma unroll
      for (int r = 0; r < 4; r++)
        C[(size_t)(row0 + i * 16 + r) * N + col0 + j * 16] = acc[i][j][r];
}

// ---------------- RMSNorm + RoPE + q-scale; one wave per (s, head) ----------------
__global__ __launch_bounds__(256) void qk_norm_rope(const float* __restrict__ qkv,
                                                    const float* __restrict__ cosb,
                                                    const float* __restrict__ sinb,
                                                    const float* __restrict__ qw,
                                                    const float* __restrict__ kw,
                                                    bf16* __restrict__ qout,
                                                    bf16* __restrict__ kout) {
  int s = blockIdx.x;
  int lane = threadIdx.x & 63;
  int w = threadIdx.x >> 6;
  int d0 = lane * 4;
  int dr = d0 & 127;
  f32x4 cv = *(const f32x4*)(cosb + s * 128 + dr);
  f32x4 sv = *(const f32x4*)(sinb + s * 128 + dr);
  bool hi = lane >= 32;
#pragma unroll
  for (int r = 0; r < 6; r++) {
    int head = r * 4 + w;  // 0..23 : 16 q heads then 8 k heads
    const float* x = qkv + (size_t)s * QKV_O + head * HDIM + d0;
    f32x4 v = *(const f32x4*)x;
    float ss = v[0] * v[0] + v[1] * v[1] + v[2] * v[2] + v[3] * v[3];
#pragma unroll
    for (int off = 32; off > 0; off >>= 1) ss += __shfl_xor(ss, off);
    float scale = rsqrtf(ss * (1.0f / HDIM) + 1e-6f);
    bool isq = head < NHEADS;
    const float* wn = isq ? qw : kw;
    f32x4 wv = *(const f32x4*)(wn + d0);
    float y[4], o[4];
#pragma unroll
    for (int i = 0; i < 4; i++) y[i] = v[i] * scale * (1.0f + wv[i]);
#pragma unroll
    for (int i = 0; i < 4; i++) {
      float py = __shfl_xor(y[i], 32);
      o[i] = hi ? (py * sv[i] + y[i] * cv[i]) : (y[i] * cv[i] - py * sv[i]);
    }
    float mult = isq ? 0.0625f : 1.0f;  // SCALING = 256^-0.5 folded into q
    bf16x4 ov = { (bf16)(o[0] * mult), (bf16)(o[1] * mult), (bf16)(o[2] * mult), (bf16)(o[3] * mult) };
    if (isq) *(bf16x4*)(qout + ((size_t)head * S_LEN + s) * HDIM + d0) = ov;
    else     *(bf16x4*)(kout + ((size_t)(head - NHEADS) * S_LEN + s) * HDIM + d0) = ov;
  }
}

// ---------------- V transpose: qkv fp32 [s][6144+h*256+d] -> vt bf16 [h][d][s] ----------------
__global__ __launch_bounds__(256) void v_transpose(const float* __restrict__ qkv, bf16* __restrict__ vt) {
  __shared__ float tile[64][65];
  int dt = blockIdx.x, st = blockIdx.y, h = blockIdx.z;
  int t = threadIdx.x;
  int d0 = dt * 64, s0 = st * 64;
#pragma unroll
  for (int i = 0; i < 16; i++) {
    int idx = i * 256 + t;
    int r = idx >> 6, c = idx & 63;  // r = s-offset, c = d-offset
    tile[r][c] = qkv[(size_t)(s0 + r) * QKV_O + 6144 + h * HDIM + d0 + c];
  }
  __syncthreads();
#pragma unroll
  for (int i = 0; i < 16; i++) {
    int idx = i * 256 + t;
    int dr = idx >> 6, sc = idx & 63;  // dr = d-offset, sc = s-offset
    vt[((size_t)h * HDIM + d0 + dr) * S_LEN + s0 + sc] = (bf16)tile[sc][dr];
  }
}

// ---------------- Flash attention: 64 q-rows/block, Bk=32 ----------------
// Fixed-max softmax (softcap bounds s to [-50,50]; p=exp(s-30) always normal).
#define PSTRIDE 40  // pbuf row stride in bf16 (80 B): conflict-free, keeps 16B align
__global__ __launch_bounds__(256) void attn_kernel(const bf16* __restrict__ q,
                                                   const bf16* __restrict__ kx,
                                                   const bf16* __restrict__ vt,
                                                   bf16* __restrict__ aout) {
  __shared__ bf16 kt[32 * 256];          // K-tile [k'][d], row-rotation swizzled by k'*8 elems
  __shared__ bf16 vtile[256 * 32];       // V-tile [d][k'], XOR chunk swizzle on k'
  __shared__ bf16 pbuf[4][16 * PSTRIDE]; // per-wave P staging (C-layout -> A-layout)
  int h = blockIdx.x;
  int y = blockIdx.y;
  int qt = (y < 16) ? y : 47 - y;  // dispatch-balance pairing: CU gets qt + (31-qt)
  int kvh = h >> 1;                // GQA: q head h uses kv head h/2
  int tid = threadIdx.x;
  int lane = tid & 63, w = tid >> 6;
  int fr = lane & 15, fq = lane >> 4;
  int qs = qt * 64;
  bf16x8 qf[8];
  const bf16* qb = q + ((size_t)h * S_LEN + qs + w * 16 + fr) * HDIM + fq * 8;
#pragma unroll
  for (int i = 0; i < 8; i++) qf[i] = *(const bf16x8*)(qb + i * 32);
  f32x4 acc[16];
#pragma unroll
  for (int i = 0; i < 16; i++) { f32x4 z = {0.f, 0.f, 0.f, 0.f}; acc[i] = z; }
  float lsum[4] = {0.f, 0.f, 0.f, 0.f};
  // staging lane roles
  int krow = w * 2 + (lane >> 5);
  int kcolr = (lane & 31) * 8;
  const bf16* kg = kx + (size_t)kvh * S_LEN * HDIM;
  int vd = w * 16 + (lane >> 2);
  int vsw = (vd >> 1) & 3;                      // V XOR swizzle
  int vcl = (lane & 3) * 8;                     // LDS chunk slot (lane-linear)
  int vcg = (((lane & 3) ^ vsw) * 8);           // permuted global chunk
  const bf16* vg = vt + (size_t)kvh * HDIM * S_LEN;
  // swizzled fragment read bases: row r of kt holds K[r][(c + r*8) & 255] at col c
  int rot0 = (fq * 8 - fr * 8) & 255;
  int rot1 = (fq * 8 - fr * 8 - 128) & 255;
  const bf16* kt0 = &kt[fr * 256];
  const bf16* kt1 = &kt[(16 + fr) * 256];
  int fsw = (fr >> 1) & 3;
  int kmax = qs + 64;
  for (int k0 = 0; k0 < kmax; k0 += 32) {
    __syncthreads();
#pragma unroll
    for (int p = 0; p < 4; p++) {
      int r = p * 8 + krow;
      int gc = (kcolr + r * 8) & 255;
      async16(kg + (size_t)(k0 + r) * HDIM + gc, &kt[r * 256 + kcolr]);
      int d = p * 64 + vd;
      async16(vg + (size_t)d * S_LEN + k0 + vcg, &vtile[d * 32 + vcl]);
    }
    __syncthreads();
    // QK^T for two 16-col score tiles
    f32x4 s0 = {0.f, 0.f, 0.f, 0.f}, s1 = {0.f, 0.f, 0.f, 0.f};
#pragma unroll
    for (int kk = 0; kk < 8; kk++) {
      bf16x8 b0 = *(const bf16x8*)(kt0 + ((kk * 32 + rot0) & 255));
      bf16x8 b1 = *(const bf16x8*)(kt1 + ((kk * 32 + rot1) & 255));
      s0 = mfma16(qf[kk], b0, s0);
      s1 = mfma16(qf[kk], b1, s1);
    }
    // softcap + causal mask + fixed-max exp: p = exp2(28.853901 - 144.26950/(u+1)),
    // u = exp2(x * 0.04*log2e)
#pragma unroll
    for (int reg = 0; reg < 4; reg++) {
      int rowg = qs + w * 16 + fq * 4 + reg;
      float u0 = __builtin_amdgcn_exp2f(0.057707802f * s0[reg]);
      float u1 = __builtin_amdgcn_exp2f(0.057707802f * s1[reg]);
      float p0 = __builtin_amdgcn_exp2f(28.853901f - 144.26950f * __builtin_amdgcn_rcpf(u0 + 1.0f));
      float p1 = __builtin_amdgcn_exp2f(28.853901f - 144.26950f * __builtin_amdgcn_rcpf(u1 + 1.0f));
      p0 = (k0 + fr <= rowg) ? p0 : 0.0f;
      p1 = (k0 + 16 + fr <= rowg) ? p1 : 0.0f;
      lsum[reg] += p0 + p1;
      pbuf[w][(fq * 4 + reg) * PSTRIDE + fr] = (bf16)p0;
      pbuf[w][(fq * 4 + reg) * PSTRIDE + 16 + fr] = (bf16)p1;
    }
    // PV: P in A-layout (same-wave LDS round trip), V^T b128 fragments (swizzled)
    bf16x8 pf = *(const bf16x8*)&pbuf[w][fr * PSTRIDE + fq * 8];
#pragma unroll
    for (int ct = 0; ct < 16; ct++) {
      bf16x8 vf = *(const bf16x8*)&vtile[(ct * 16 + fr) * 32 + (fq ^ fsw) * 8];
      acc[ct] = mfma16(pf, vf, acc[ct]);
    }
  }
  // final l reduction over the 16 fr lanes of each row, then divide
  float rl[4];
#pragma unroll
  for (int reg = 0; reg < 4; reg++) {
    float l = lsum[reg];
    l += __shfl_xor(l, 1);
    l += __shfl_xor(l, 2);
    l += __shfl_xor(l, 4);
    l += __shfl_xor(l, 8);
    rl[reg] = 1.0f / l;
  }
#pragma unroll
  for (int ct = 0; ct < 16; ct++)
#pragma unroll
    for (int reg = 0; reg < 4; reg++)
      aout[(size_t)(qs + w * 16 + fq * 4 + reg) * O_IN + h * HDIM + ct * 16 + fr] =
          (bf16)(acc[ct][reg] * rl[reg]);
}

extern "C" void kernel_launch(void* const* d_in, const int* in_sizes, int n_in,
                              void* d_out, int out_size, void* d_ws, size_t ws_size,
                              hipStream_t stream) {
  const float* hidden = (const float*)d_in[0];
  const float* cosb   = (const float*)d_in[1];
  const float* sinb   = (const float*)d_in[2];
  const float* wqkv   = (const float*)d_in[7];
  const float* wo     = (const float*)d_in[8];
  const float* qnw    = (const float*)d_in[9];
  const float* knw    = (const float*)d_in[10];
  float* out = (float*)d_out;
  char* ws = (char*)d_ws;
  bf16*  h_bf    = (bf16*)(ws + 0);          // 2048*3584*2   = 14,680,064
  bf16*  wqkv_bf = (bf16*)(ws + 14680064);   // 8192*3584*2   = 58,720,256
  bf16*  wo_bf   = (bf16*)(ws + 73400320);   // 3584*4096*2   = 29,360,128
  float* qkv     = (float*)(ws + 102760448); // 2048*8192*4   = 67,108,864
  bf16*  qb      = (bf16*)(ws + 169869312);  // 16*2048*256*2 = 16,777,216
  bf16*  kb      = (bf16*)(ws + 186646528);  // 8*2048*256*2  =  8,388,608
  bf16*  vtb     = (bf16*)(ws + 195035136);  // 8*256*2048*2  =  8,388,608
  bf16*  attnb   = (bf16*)(ws + 203423744);  // 2048*4096*2   = 16,777,216

  cast_kernel<<<7168, 256, 0, stream>>>(hidden, h_bf, 1835008);
  cast_kernel<<<28672, 256, 0, stream>>>(wqkv, wqkv_bf, 7340032);
  cast_kernel<<<14336, 256, 0, stream>>>(wo, wo_bf, 3670016);
  gemm_nt<<<dim3(64, 16), 256, 0, stream>>>(h_bf, wqkv_bf, qkv, 2048, 8192, 3584);
  qk_norm_rope<<<2048, 256, 0, stream>>>(qkv, cosb, sinb, qnw, knw, qb, kb);
  v_transpose<<<dim3(4, 32, 8), 256, 0, stream>>>(qkv, vtb);
  attn_kernel<<<dim3(16, 32), 256, 0, stream>>>(qb, kb, vtb, attnb);
  gemm_nt<<<dim3(28, 16), 256, 0, stream>>>(attnb, wo_bf, out, 2048, 3584, 4096);
}